// Round 1
// baseline (441.850 us; speedup 1.0000x reference)
//
#include <hip/hip_runtime.h>
#include <hip/hip_bf16.h>

#define T_TOKENS 2048
#define NE 8
#define HID 1024
#define INTER_ 2048
#define NPAIR (T_TOKENS * 2)

typedef unsigned short u16;
typedef __attribute__((ext_vector_type(4))) float f32x4;
typedef __attribute__((ext_vector_type(8))) short s16x8;

__device__ __forceinline__ u16 f2b(float f) {
    union { float f; unsigned u; } v; v.f = f;
    unsigned r = v.u + 0x7fffu + ((v.u >> 16) & 1u);
    return (u16)(r >> 16);
}
__device__ __forceinline__ float b2f(u16 b) {
    union { unsigned u; float f; } v; v.u = ((unsigned)b) << 16;
    return v.f;
}

// ---------------- routing ----------------
__global__ void route_kernel(const float* __restrict__ logits,
                             int* cnt, int* tokE, float* tokW) {
    int t = blockIdx.x * 256 + threadIdx.x;
    if (t >= T_TOKENS) return;
    float l[NE];
#pragma unroll
    for (int i = 0; i < NE; i++) l[i] = logits[t * NE + i];
    int i0 = 0; float m0 = l[0];
#pragma unroll
    for (int i = 1; i < NE; i++) if (l[i] > m0) { m0 = l[i]; i0 = i; }
    int i1 = -1; float m1 = -1e30f;
#pragma unroll
    for (int i = 0; i < NE; i++) if (i != i0 && l[i] > m1) { m1 = l[i]; i1 = i; }
    float w0 = 1.f / (1.f + expf(m1 - m0));   // softmax over [m0,m1], m0 >= m1
    tokE[2 * t] = i0; tokE[2 * t + 1] = i1;
    tokW[2 * t] = w0; tokW[2 * t + 1] = 1.f - w0;
    atomicAdd(&cnt[i0], 1);
    atomicAdd(&cnt[i1], 1);
}

__global__ void scan_kernel(const int* __restrict__ cnt, int* offs, int* cursor) {
    if (threadIdx.x == 0 && blockIdx.x == 0) {
        int a = 0;
        for (int e = 0; e < NE; e++) { offs[e] = a; cursor[e] = a; a += cnt[e]; }
        offs[NE] = a;
    }
}

__global__ void scatter_kernel(const int* __restrict__ tokE, int* cursor,
                               int* pair_tok, int* pair_slot) {
    int t = blockIdx.x * 256 + threadIdx.x;
    if (t >= T_TOKENS) return;
#pragma unroll
    for (int k = 0; k < 2; k++) {
        int e = tokE[2 * t + k];
        int slot = atomicAdd(&cursor[e], 1);
        pair_tok[slot] = t;
        pair_slot[2 * t + k] = slot;
    }
}

// ---------------- fp32 -> bf16 convert of x ----------------
__global__ void cvt_x_kernel(const float* __restrict__ x, u16* __restrict__ xb) {
    int i = blockIdx.x * 256 + threadIdx.x;   // one float4 per thread, exact grid
    float4 v = ((const float4*)x)[i];
    ushort4 b;
    b.x = f2b(v.x); b.y = f2b(v.y); b.z = f2b(v.z); b.w = f2b(v.w);
    ((ushort4*)xb)[i] = b;
}

// ---------------- weight transpose+convert: W[e][K][N] f32 -> Wt[e][N][K] bf16 ----------------
__global__ __launch_bounds__(256) void transpose_kernel(const float* __restrict__ W,
                                                        u16* __restrict__ Wt,
                                                        int K, int N) {
    int e = blockIdx.z;
    const float* Win = W + (size_t)e * K * N;
    u16* Wout = Wt + (size_t)e * N * K;
    int nb = blockIdx.x * 64, kb = blockIdx.y * 64;
    __shared__ __align__(16) u16 tile[64 * 72];
    int tid = threadIdx.x;
#pragma unroll
    for (int p = 0; p < 4; p++) {
        int c = tid + p * 256;
        int r = c >> 4, c4 = c & 15;
        float4 v = *(const float4*)&Win[(size_t)(kb + r) * N + nb + c4 * 4];
        ushort4 b;
        b.x = f2b(v.x); b.y = f2b(v.y); b.z = f2b(v.z); b.w = f2b(v.w);
        *(ushort4*)&tile[r * 72 + c4 * 4] = b;
    }
    __syncthreads();
#pragma unroll
    for (int p = 0; p < 2; p++) {
        int c = tid + p * 256;
        int n = c >> 3, k8 = c & 7;
        __align__(16) u16 tmp[8];
#pragma unroll
        for (int j = 0; j < 8; j++) tmp[j] = tile[(k8 * 8 + j) * 72 + n];
        *(uint4*)&Wout[(size_t)(nb + n) * K + kb + k8 * 8] = *(const uint4*)tmp;
    }
}

// ---------------- grouped MFMA GEMM ----------------
// C[slot][n] = sum_k A[row(slot)][k] * Bt[e][n][k]
// A: bf16 [*, K]; Bt: bf16 [E][N][K]; tiles 128x128x32, 4 waves/block.
template <bool GATHER, bool STOREBF>
__global__ __launch_bounds__(256) void gemm_kernel(const u16* __restrict__ A,
                                                   const u16* __restrict__ Bt,
                                                   const int* __restrict__ pair_tok,
                                                   const int* __restrict__ offs,
                                                   void* __restrict__ Cout,
                                                   int K, int N) {
    int e = blockIdx.z;
    int off = offs[e];
    int cnt = offs[e + 1] - off;
    int row0 = blockIdx.y * 128;
    if (row0 >= cnt) return;
    int nt = blockIdx.x * 128;

    __shared__ __align__(16) u16 As[128 * 40];
    __shared__ __align__(16) u16 Bs[128 * 40];

    int tid = threadIdx.x;
    int wave = tid >> 6, lane = tid & 63;

    int r0s = tid >> 2, seg0 = tid & 3;
    const u16* arow_ptr[2];
#pragma unroll
    for (int h = 0; h < 2; h++) {
        int r = r0s + h * 64;
        int mr = row0 + r; if (mr > cnt - 1) mr = cnt - 1;
        int arow;
        if (GATHER) arow = pair_tok[off + mr];
        else        arow = off + mr;
        arow_ptr[h] = A + (size_t)arow * K + seg0 * 8;
    }
    const u16* brow_ptr[2];
#pragma unroll
    for (int h = 0; h < 2; h++) {
        int r = r0s + h * 64;
        brow_ptr[h] = Bt + (size_t)e * N * K + (size_t)(nt + r) * K + seg0 * 8;
    }

    int wr = (wave >> 1) * 64, wc = (wave & 1) * 64;
    int fm = lane & 15, fk = (lane >> 4) * 8;

    f32x4 acc[4][4];
#pragma unroll
    for (int i = 0; i < 4; i++)
#pragma unroll
        for (int j = 0; j < 4; j++) acc[i][j] = (f32x4){0.f, 0.f, 0.f, 0.f};

    for (int kb = 0; kb < K; kb += 32) {
#pragma unroll
        for (int h = 0; h < 2; h++) {
            int r = r0s + h * 64;
            uint4 av = *(const uint4*)(arow_ptr[h] + kb);
            *(uint4*)&As[r * 40 + seg0 * 8] = av;
            uint4 bv = *(const uint4*)(brow_ptr[h] + kb);
            *(uint4*)&Bs[r * 40 + seg0 * 8] = bv;
        }
        __syncthreads();
        s16x8 af[4], bfr[4];
#pragma unroll
        for (int i = 0; i < 4; i++)
            af[i] = *(const s16x8*)&As[(wr + i * 16 + fm) * 40 + fk];
#pragma unroll
        for (int j = 0; j < 4; j++)
            bfr[j] = *(const s16x8*)&Bs[(wc + j * 16 + fm) * 40 + fk];
#pragma unroll
        for (int i = 0; i < 4; i++)
#pragma unroll
            for (int j = 0; j < 4; j++)
                acc[i][j] = __builtin_amdgcn_mfma_f32_16x16x32_bf16(af[i], bfr[j], acc[i][j], 0, 0, 0);
        __syncthreads();
    }

    // epilogue: C/D layout col=lane&15, row=(lane>>4)*4+reg  [verified m89/m91]
    int r4 = (lane >> 4) * 4, cc = lane & 15;
#pragma unroll
    for (int i = 0; i < 4; i++) {
#pragma unroll
        for (int reg = 0; reg < 4; reg++) {
            int rr = wr + i * 16 + r4 + reg;
            if (row0 + rr < cnt) {
                size_t slot = (size_t)(off + row0 + rr);
#pragma unroll
                for (int j = 0; j < 4; j++) {
                    int col = nt + wc + j * 16 + cc;
                    float v = acc[i][j][reg];
                    if constexpr (STOREBF) ((u16*)Cout)[slot * N + col] = f2b(v);
                    else                   ((float*)Cout)[slot * N + col] = v;
                }
            }
        }
    }
}

// ---------------- SwiGLU elementwise ----------------
__global__ void swiglu_kernel(const u16* __restrict__ h0, const u16* __restrict__ h1,
                              u16* __restrict__ inter) {
    int i = blockIdx.x * 256 + threadIdx.x;   // one ushort4 per thread, exact grid
    ushort4 a = ((const ushort4*)h0)[i];
    ushort4 b = ((const ushort4*)h1)[i];
    float xs[4] = { b2f(a.x), b2f(a.y), b2f(a.z), b2f(a.w) };
    float ys[4] = { b2f(b.x), b2f(b.y), b2f(b.z), b2f(b.w) };
    u16 o[4];
#pragma unroll
    for (int j = 0; j < 4; j++) {
        float s = xs[j] / (1.f + __expf(-xs[j]));   // silu
        o[j] = f2b(s * ys[j]);
    }
    ushort4 r; r.x = o[0]; r.y = o[1]; r.z = o[2]; r.w = o[3];
    ((ushort4*)inter)[i] = r;
}

// ---------------- weighted combine back to token order ----------------
__global__ void combine_kernel(const float* __restrict__ y, const int* __restrict__ pair_slot,
                               const float* __restrict__ tokW, float* __restrict__ out) {
    int i = blockIdx.x * 256 + threadIdx.x;   // one float4 per thread, exact grid
    int t = i >> 8;           // HID/4 = 256 float4 per token
    int h4 = i & 255;
    int s0 = pair_slot[2 * t], s1 = pair_slot[2 * t + 1];
    float w0 = tokW[2 * t], w1 = tokW[2 * t + 1];
    float4 a = ((const float4*)y)[(size_t)s0 * 256 + h4];
    float4 b = ((const float4*)y)[(size_t)s1 * 256 + h4];
    float4 r;
    r.x = w0 * a.x + w1 * b.x;
    r.y = w0 * a.y + w1 * b.y;
    r.z = w0 * a.z + w1 * b.z;
    r.w = w0 * a.w + w1 * b.w;
    ((float4*)out)[i] = r;
}

extern "C" void kernel_launch(void* const* d_in, const int* in_sizes, int n_in,
                              void* d_out, int out_size, void* d_ws, size_t ws_size,
                              hipStream_t stream) {
    (void)in_sizes; (void)n_in; (void)out_size; (void)ws_size;
    const float* x   = (const float*)d_in[0];
    const float* rl  = (const float*)d_in[1];
    const float* wi0 = (const float*)d_in[2];
    const float* wi1 = (const float*)d_in[3];
    const float* wo  = (const float*)d_in[4];
    float* out = (float*)d_out;

    char* p = (char*)d_ws;
    auto alloc = [&](size_t bytes) -> void* {
        void* r = (void*)p;
        p += (bytes + 255) & ~(size_t)255;
        return r;
    };
    u16* xb   = (u16*)alloc((size_t)T_TOKENS * HID * 2);          // 4 MB
    u16* wt0  = (u16*)alloc((size_t)NE * HID * INTER_ * 2);       // 32 MB  [E][I][H]
    u16* wt1  = (u16*)alloc((size_t)NE * HID * INTER_ * 2);       // 32 MB
    u16* wto  = (u16*)alloc((size_t)NE * HID * INTER_ * 2);       // 32 MB  [E][H][I]
    u16* h0   = (u16*)alloc((size_t)NPAIR * INTER_ * 2);          // 16 MB
    u16* h1   = (u16*)alloc((size_t)NPAIR * INTER_ * 2);          // 16 MB
    u16* intr = (u16*)alloc((size_t)NPAIR * INTER_ * 2);          // 16 MB
    int* cnt      = (int*)alloc(NE * sizeof(int));
    int* offs     = (int*)alloc((NE + 1) * sizeof(int));
    int* cursor   = (int*)alloc(NE * sizeof(int));
    int* tokE     = (int*)alloc(NPAIR * sizeof(int));
    float* tokW   = (float*)alloc(NPAIR * sizeof(float));
    int* pair_tok = (int*)alloc(NPAIR * sizeof(int));
    int* pair_slot= (int*)alloc(NPAIR * sizeof(int));
    float* y = (float*)h0;   // alias: h0 (16 MB) dead after swiglu; y is 16 MB fp32

    hipMemsetAsync(cnt, 0, NE * sizeof(int), stream);
    route_kernel<<<T_TOKENS / 256, 256, 0, stream>>>(rl, cnt, tokE, tokW);
    scan_kernel<<<1, 64, 0, stream>>>(cnt, offs, cursor);
    scatter_kernel<<<T_TOKENS / 256, 256, 0, stream>>>(tokE, cursor, pair_tok, pair_slot);
    cvt_x_kernel<<<T_TOKENS * HID / 4 / 256, 256, 0, stream>>>(x, xb);

    dim3 tgi(INTER_ / 64, HID / 64, NE);
    transpose_kernel<<<tgi, 256, 0, stream>>>(wi0, wt0, HID, INTER_);
    transpose_kernel<<<tgi, 256, 0, stream>>>(wi1, wt1, HID, INTER_);
    dim3 tgo(HID / 64, INTER_ / 64, NE);
    transpose_kernel<<<tgo, 256, 0, stream>>>(wo, wto, INTER_, HID);

    dim3 g1(INTER_ / 128, 16, NE);
    gemm_kernel<true, true><<<g1, 256, 0, stream>>>(xb, wt0, pair_tok, offs, h0, HID, INTER_);
    gemm_kernel<true, true><<<g1, 256, 0, stream>>>(xb, wt1, pair_tok, offs, h1, HID, INTER_);
    swiglu_kernel<<<NPAIR * INTER_ / 4 / 256, 256, 0, stream>>>(h0, h1, intr);
    dim3 g2(HID / 128, 16, NE);
    gemm_kernel<false, false><<<g2, 256, 0, stream>>>(intr, wto, nullptr, offs, y, INTER_, HID);
    combine_kernel<<<T_TOKENS * HID / 4 / 256, 256, 0, stream>>>(y, pair_slot, tokW, out);
}

// Round 2
// 391.341 us; speedup vs baseline: 1.1291x; 1.1291x over previous
//
#include <hip/hip_runtime.h>
#include <hip/hip_bf16.h>

#define T_TOKENS 2048
#define NE 8
#define HID 1024
#define INTER_ 2048
#define NPAIR (T_TOKENS * 2)

typedef unsigned short u16;
typedef __attribute__((ext_vector_type(4))) float f32x4;
typedef __attribute__((ext_vector_type(8))) short s16x8;

__device__ __forceinline__ u16 f2b(float f) {
    union { float f; unsigned u; } v; v.f = f;
    unsigned r = v.u + 0x7fffu + ((v.u >> 16) & 1u);
    return (u16)(r >> 16);
}

// async global->LDS, 16B per lane; LDS dest must be wave-uniform base (+lane*16)
__device__ __forceinline__ void gl_lds16(const u16* g, u16* l) {
    __builtin_amdgcn_global_load_lds(
        (const __attribute__((address_space(1))) unsigned int*)g,
        (__attribute__((address_space(3))) unsigned int*)l, 16, 0, 0);
}

// ---------------- routing ----------------
__global__ void route_kernel(const float* __restrict__ logits,
                             int* cnt, int* tokE, float* tokW) {
    int t = blockIdx.x * 256 + threadIdx.x;
    if (t >= T_TOKENS) return;
    float l[NE];
#pragma unroll
    for (int i = 0; i < NE; i++) l[i] = logits[t * NE + i];
    int i0 = 0; float m0 = l[0];
#pragma unroll
    for (int i = 1; i < NE; i++) if (l[i] > m0) { m0 = l[i]; i0 = i; }
    int i1 = -1; float m1 = -1e30f;
#pragma unroll
    for (int i = 0; i < NE; i++) if (i != i0 && l[i] > m1) { m1 = l[i]; i1 = i; }
    float w0 = 1.f / (1.f + expf(m1 - m0));
    tokE[2 * t] = i0; tokE[2 * t + 1] = i1;
    tokW[2 * t] = w0; tokW[2 * t + 1] = 1.f - w0;
    atomicAdd(&cnt[i0], 1);
    atomicAdd(&cnt[i1], 1);
}

__global__ void scan_kernel(const int* __restrict__ cnt, int* offs, int* cursor) {
    if (threadIdx.x == 0 && blockIdx.x == 0) {
        int a = 0;
        for (int e = 0; e < NE; e++) { offs[e] = a; cursor[e] = a; a += cnt[e]; }
        offs[NE] = a;
    }
}

__global__ void scatter_kernel(const int* __restrict__ tokE, int* cursor,
                               int* pair_tok, int* pair_slot) {
    int t = blockIdx.x * 256 + threadIdx.x;
    if (t >= T_TOKENS) return;
#pragma unroll
    for (int k = 0; k < 2; k++) {
        int e = tokE[2 * t + k];
        int slot = atomicAdd(&cursor[e], 1);
        pair_tok[slot] = t;
        pair_slot[2 * t + k] = slot;
    }
}

// ---------------- fp32 -> bf16 convert of x ----------------
__global__ void cvt_x_kernel(const float* __restrict__ x, u16* __restrict__ xb) {
    int i = blockIdx.x * 256 + threadIdx.x;
    float4 v = ((const float4*)x)[i];
    ushort4 b;
    b.x = f2b(v.x); b.y = f2b(v.y); b.z = f2b(v.z); b.w = f2b(v.w);
    ((ushort4*)xb)[i] = b;
}

// ---------------- weight transpose+convert: W[e][K][N] f32 -> Wt[e][N][K] bf16 ----------------
// phase2 reads are conflict-free (lanes sweep consecutive n); writes are 16B scattered
// but every 64B line is fully written within the block, so L2 assembles full lines.
__global__ __launch_bounds__(256) void transpose_kernel(const float* __restrict__ W,
                                                        u16* __restrict__ Wt,
                                                        int K, int N) {
    int e = blockIdx.z;
    const float* Win = W + (size_t)e * K * N;
    u16* Wout = Wt + (size_t)e * N * K;
    int nb = blockIdx.x * 64, kb = blockIdx.y * 64;
    __shared__ __align__(16) u16 tile[64 * 68];   // stride 68 u16 = 136 B
    int tid = threadIdx.x;
#pragma unroll
    for (int p = 0; p < 4; p++) {
        int c = tid + p * 256;
        int r = c >> 4, c4 = c & 15;
        float4 v = *(const float4*)&Win[(size_t)(kb + r) * N + nb + c4 * 4];
        ushort4 b;
        b.x = f2b(v.x); b.y = f2b(v.y); b.z = f2b(v.z); b.w = f2b(v.w);
        *(ushort4*)&tile[r * 68 + c4 * 4] = b;
    }
    __syncthreads();
#pragma unroll
    for (int p = 0; p < 2; p++) {
        int k8 = p * 4 + (tid >> 6);   // wave-uniform
        int n = tid & 63;
        __align__(16) u16 tmp[8];
#pragma unroll
        for (int j = 0; j < 8; j++) tmp[j] = tile[(k8 * 8 + j) * 68 + n];
        *(uint4*)&Wout[(size_t)(nb + n) * K + kb + k8 * 8] = *(const uint4*)tmp;
    }
}

// ---------------- fused up-proj: h0 = x@wi0, h1 = x@wi1, intr = silu(h0)*h1 ----------------
// A: xb [T][HID] bf16 gathered via pair_tok; B0t/B1t: [E][INTER][HID] bf16.
// 128x128 tile, 4 waves, global_load_lds staging (unpadded LDS).
__global__ __launch_bounds__(256, 2) void fused_up_kernel(
        const u16* __restrict__ A, const u16* __restrict__ B0t, const u16* __restrict__ B1t,
        const int* __restrict__ pair_tok, const int* __restrict__ offs,
        u16* __restrict__ intr) {
    int e = blockIdx.z;
    int off = offs[e];
    int cnt = offs[e + 1] - off;
    int row0 = blockIdx.y * 128;
    if (row0 >= cnt) return;
    int nt = blockIdx.x * 128;

    __shared__ __align__(16) u16 As[128 * 32];
    __shared__ __align__(16) u16 Bs0[128 * 32];
    __shared__ __align__(16) u16 Bs1[128 * 32];

    int tid = threadIdx.x;
    int wave = tid >> 6, lane = tid & 63;

    const u16* gA[2]; const u16* gB0[2]; const u16* gB1[2];
    u16 *lA[2], *lB0[2], *lB1[2];
    const size_t eNK = (size_t)e * INTER_ * HID;
#pragma unroll
    for (int h = 0; h < 2; h++) {
        int c = 2 * wave + h;                 // chunk 0..7 (16 rows each)
        int r = c * 16 + (lane >> 2);
        int seg = lane & 3;
        int mr = row0 + r; if (mr > cnt - 1) mr = cnt - 1;
        int arow = pair_tok[off + mr];
        gA[h]  = A + (size_t)arow * HID + seg * 8;
        gB0[h] = B0t + eNK + (size_t)(nt + r) * HID + seg * 8;
        gB1[h] = B1t + eNK + (size_t)(nt + r) * HID + seg * 8;
        lA[h]  = As  + c * 512;
        lB0[h] = Bs0 + c * 512;
        lB1[h] = Bs1 + c * 512;
    }

    int wr = (wave >> 1) * 64, wc = (wave & 1) * 64;
    int fm = lane & 15, fk = (lane >> 4) * 8;

    f32x4 acc0[4][4], acc1[4][4];
#pragma unroll
    for (int i = 0; i < 4; i++)
#pragma unroll
        for (int j = 0; j < 4; j++) {
            acc0[i][j] = (f32x4){0.f, 0.f, 0.f, 0.f};
            acc1[i][j] = (f32x4){0.f, 0.f, 0.f, 0.f};
        }

    for (int kb = 0; kb < HID; kb += 32) {
#pragma unroll
        for (int h = 0; h < 2; h++) {
            gl_lds16(gA[h] + kb, lA[h]);
            gl_lds16(gB0[h] + kb, lB0[h]);
            gl_lds16(gB1[h] + kb, lB1[h]);
        }
        __syncthreads();
        s16x8 af[4];
#pragma unroll
        for (int i = 0; i < 4; i++)
            af[i] = *(const s16x8*)&As[(wr + i * 16 + fm) * 32 + fk];
#pragma unroll
        for (int j = 0; j < 4; j++) {
            s16x8 b0 = *(const s16x8*)&Bs0[(wc + j * 16 + fm) * 32 + fk];
            s16x8 b1 = *(const s16x8*)&Bs1[(wc + j * 16 + fm) * 32 + fk];
#pragma unroll
            for (int i = 0; i < 4; i++) {
                acc0[i][j] = __builtin_amdgcn_mfma_f32_16x16x32_bf16(af[i], b0, acc0[i][j], 0, 0, 0);
                acc1[i][j] = __builtin_amdgcn_mfma_f32_16x16x32_bf16(af[i], b1, acc1[i][j], 0, 0, 0);
            }
        }
        __syncthreads();
    }

    // epilogue: C/D layout col=lane&15, row=(lane>>4)*4+reg; fuse SwiGLU
    int r4 = (lane >> 4) * 4, cc = lane & 15;
#pragma unroll
    for (int i = 0; i < 4; i++) {
#pragma unroll
        for (int reg = 0; reg < 4; reg++) {
            int rr = wr + i * 16 + r4 + reg;
            if (row0 + rr < cnt) {
                size_t slot = (size_t)(off + row0 + rr);
#pragma unroll
                for (int j = 0; j < 4; j++) {
                    int col = nt + wc + j * 16 + cc;
                    float a = acc0[i][j][reg];
                    float b = acc1[i][j][reg];
                    float s = a / (1.f + __expf(-a)) * b;
                    intr[slot * INTER_ + col] = f2b(s);
                }
            }
        }
    }
}

// ---------------- down-proj: y = intr @ wo, split-K=2 into two fp32 partials ----------------
// A: intr [NPAIR][INTER] bf16 (rows already expert-grouped); Bt: wto [E][HID][INTER] bf16.
__global__ __launch_bounds__(256, 2) void down_kernel(
        const u16* __restrict__ A, const u16* __restrict__ Bt,
        const int* __restrict__ offs, float* __restrict__ ypart) {
    int e = blockIdx.z >> 1, ks = blockIdx.z & 1;
    int off = offs[e];
    int cnt = offs[e + 1] - off;
    int row0 = blockIdx.y * 128;
    if (row0 >= cnt) return;
    int nt = blockIdx.x * 128;

    __shared__ __align__(16) u16 As[128 * 32];
    __shared__ __align__(16) u16 Bs[128 * 32];

    int tid = threadIdx.x;
    int wave = tid >> 6, lane = tid & 63;

    const u16* gA[2]; const u16* gB[2];
    u16 *lA[2], *lB[2];
    const size_t eNK = (size_t)e * HID * INTER_;
#pragma unroll
    for (int h = 0; h < 2; h++) {
        int c = 2 * wave + h;
        int r = c * 16 + (lane >> 2);
        int seg = lane & 3;
        int mr = row0 + r; if (mr > cnt - 1) mr = cnt - 1;
        gA[h] = A + (size_t)(off + mr) * INTER_ + seg * 8;
        gB[h] = Bt + eNK + (size_t)(nt + r) * INTER_ + seg * 8;
        lA[h] = As + c * 512;
        lB[h] = Bs + c * 512;
    }

    int wr = (wave >> 1) * 64, wc = (wave & 1) * 64;
    int fm = lane & 15, fk = (lane >> 4) * 8;

    f32x4 acc[4][4];
#pragma unroll
    for (int i = 0; i < 4; i++)
#pragma unroll
        for (int j = 0; j < 4; j++) acc[i][j] = (f32x4){0.f, 0.f, 0.f, 0.f};

    int kend = ks * 1024 + 1024;
    for (int kb = ks * 1024; kb < kend; kb += 32) {
#pragma unroll
        for (int h = 0; h < 2; h++) {
            gl_lds16(gA[h] + kb, lA[h]);
            gl_lds16(gB[h] + kb, lB[h]);
        }
        __syncthreads();
        s16x8 af[4], bfr[4];
#pragma unroll
        for (int i = 0; i < 4; i++)
            af[i] = *(const s16x8*)&As[(wr + i * 16 + fm) * 32 + fk];
#pragma unroll
        for (int j = 0; j < 4; j++)
            bfr[j] = *(const s16x8*)&Bs[(wc + j * 16 + fm) * 32 + fk];
#pragma unroll
        for (int i = 0; i < 4; i++)
#pragma unroll
            for (int j = 0; j < 4; j++)
                acc[i][j] = __builtin_amdgcn_mfma_f32_16x16x32_bf16(af[i], bfr[j], acc[i][j], 0, 0, 0);
        __syncthreads();
    }

    int r4 = (lane >> 4) * 4, cc = lane & 15;
    float* yout = ypart + (size_t)ks * NPAIR * HID;
#pragma unroll
    for (int i = 0; i < 4; i++) {
#pragma unroll
        for (int reg = 0; reg < 4; reg++) {
            int rr = wr + i * 16 + r4 + reg;
            if (row0 + rr < cnt) {
                size_t slot = (size_t)(off + row0 + rr);
#pragma unroll
                for (int j = 0; j < 4; j++) {
                    int col = nt + wc + j * 16 + cc;
                    yout[slot * HID + col] = acc[i][j][reg];
                }
            }
        }
    }
}

// ---------------- weighted combine (sums the two split-K partials) ----------------
__global__ void combine_kernel(const float* __restrict__ y0, const float* __restrict__ y1,
                               const int* __restrict__ pair_slot,
                               const float* __restrict__ tokW, float* __restrict__ out) {
    int i = blockIdx.x * 256 + threadIdx.x;
    int t = i >> 8;
    int h4 = i & 255;
    int s0 = pair_slot[2 * t], s1 = pair_slot[2 * t + 1];
    float w0 = tokW[2 * t], w1 = tokW[2 * t + 1];
    float4 a0 = ((const float4*)y0)[(size_t)s0 * 256 + h4];
    float4 a1 = ((const float4*)y1)[(size_t)s0 * 256 + h4];
    float4 b0 = ((const float4*)y0)[(size_t)s1 * 256 + h4];
    float4 b1 = ((const float4*)y1)[(size_t)s1 * 256 + h4];
    float4 r;
    r.x = w0 * (a0.x + a1.x) + w1 * (b0.x + b1.x);
    r.y = w0 * (a0.y + a1.y) + w1 * (b0.y + b1.y);
    r.z = w0 * (a0.z + a1.z) + w1 * (b0.z + b1.z);
    r.w = w0 * (a0.w + a1.w) + w1 * (b0.w + b1.w);
    ((float4*)out)[i] = r;
}

extern "C" void kernel_launch(void* const* d_in, const int* in_sizes, int n_in,
                              void* d_out, int out_size, void* d_ws, size_t ws_size,
                              hipStream_t stream) {
    (void)in_sizes; (void)n_in; (void)out_size; (void)ws_size;
    const float* x   = (const float*)d_in[0];
    const float* rl  = (const float*)d_in[1];
    const float* wi0 = (const float*)d_in[2];
    const float* wi1 = (const float*)d_in[3];
    const float* wo  = (const float*)d_in[4];
    float* out = (float*)d_out;

    char* p = (char*)d_ws;
    auto alloc = [&](size_t bytes) -> void* {
        void* r = (void*)p;
        p += (bytes + 255) & ~(size_t)255;
        return r;
    };
    u16* xb   = (u16*)alloc((size_t)T_TOKENS * HID * 2);          // 4 MB
    u16* wt0  = (u16*)alloc((size_t)NE * HID * INTER_ * 2);       // 32 MB  [E][I][H]
    u16* wt1  = (u16*)alloc((size_t)NE * HID * INTER_ * 2);       // 32 MB
    u16* wto  = (u16*)alloc((size_t)NE * HID * INTER_ * 2);       // 32 MB  [E][H][I]
    u16* intr = (u16*)alloc((size_t)NPAIR * INTER_ * 2);          // 16 MB
    float* ypart = (float*)alloc((size_t)2 * NPAIR * HID * 4);    // 32 MB
    int* cnt      = (int*)alloc(NE * sizeof(int));
    int* offs     = (int*)alloc((NE + 1) * sizeof(int));
    int* cursor   = (int*)alloc(NE * sizeof(int));
    int* tokE     = (int*)alloc(NPAIR * sizeof(int));
    float* tokW   = (float*)alloc(NPAIR * sizeof(float));
    int* pair_tok = (int*)alloc(NPAIR * sizeof(int));
    int* pair_slot= (int*)alloc(NPAIR * sizeof(int));

    hipMemsetAsync(cnt, 0, NE * sizeof(int), stream);
    route_kernel<<<T_TOKENS / 256, 256, 0, stream>>>(rl, cnt, tokE, tokW);
    scan_kernel<<<1, 64, 0, stream>>>(cnt, offs, cursor);
    scatter_kernel<<<T_TOKENS / 256, 256, 0, stream>>>(tokE, cursor, pair_tok, pair_slot);
    cvt_x_kernel<<<T_TOKENS * HID / 4 / 256, 256, 0, stream>>>(x, xb);

    dim3 tgi(INTER_ / 64, HID / 64, NE);
    transpose_kernel<<<tgi, 256, 0, stream>>>(wi0, wt0, HID, INTER_);
    transpose_kernel<<<tgi, 256, 0, stream>>>(wi1, wt1, HID, INTER_);
    dim3 tgo(HID / 64, INTER_ / 64, NE);
    transpose_kernel<<<tgo, 256, 0, stream>>>(wo, wto, INTER_, HID);

    dim3 g1(INTER_ / 128, 16, NE);
    fused_up_kernel<<<g1, 256, 0, stream>>>(xb, wt0, wt1, pair_tok, offs, intr);
    dim3 g2(HID / 128, 16, NE * 2);
    down_kernel<<<g2, 256, 0, stream>>>(intr, wto, offs, ypart);
    combine_kernel<<<T_TOKENS * HID / 4 / 256, 256, 0, stream>>>(
        ypart, ypart + (size_t)NPAIR * HID, pair_slot, tokW, out);
}

// Round 3
// 349.239 us; speedup vs baseline: 1.2652x; 1.1206x over previous
//
#include <hip/hip_runtime.h>
#include <hip/hip_bf16.h>

#define T_TOKENS 2048
#define NE 8
#define HID 1024
#define INTER_ 2048
#define NPAIR (T_TOKENS * 2)

typedef unsigned short u16;
typedef __attribute__((ext_vector_type(4))) float f32x4;
typedef __attribute__((ext_vector_type(8))) short s16x8;

__device__ __forceinline__ u16 f2b(float f) {
    union { float f; unsigned u; } v; v.f = f;
    unsigned r = v.u + 0x7fffu + ((v.u >> 16) & 1u);
    return (u16)(r >> 16);
}

// async global->LDS, 16B per lane; LDS dest is wave-uniform base + lane*16
__device__ __forceinline__ void gl_lds16(const u16* g, u16* l) {
    __builtin_amdgcn_global_load_lds(
        (const __attribute__((address_space(1))) unsigned int*)g,
        (__attribute__((address_space(3))) unsigned int*)l, 16, 0, 0);
}

// ---------------- routing: top2 + softmax + grouped scatter, one block ----------------
__global__ __launch_bounds__(256) void route_all(const float* __restrict__ logits,
                                                 int* __restrict__ offs,
                                                 int* __restrict__ pair_tok,
                                                 float* __restrict__ pair_w) {
    __shared__ int s_cnt[NE];
    __shared__ int s_cur[NE];
    __shared__ short s_e0[T_TOKENS];
    __shared__ short s_e1[T_TOKENS];
    __shared__ float s_w0[T_TOKENS];
    int tid = threadIdx.x;
    if (tid < NE) s_cnt[tid] = 0;
    __syncthreads();
    for (int t = tid; t < T_TOKENS; t += 256) {
        float l[NE];
#pragma unroll
        for (int i = 0; i < NE; i++) l[i] = logits[t * NE + i];
        int i0 = 0; float m0 = l[0];
#pragma unroll
        for (int i = 1; i < NE; i++) if (l[i] > m0) { m0 = l[i]; i0 = i; }
        int i1 = -1; float m1 = -1e30f;
#pragma unroll
        for (int i = 0; i < NE; i++) if (i != i0 && l[i] > m1) { m1 = l[i]; i1 = i; }
        float w0 = 1.f / (1.f + __expf(m1 - m0));
        s_e0[t] = (short)i0; s_e1[t] = (short)i1; s_w0[t] = w0;
        atomicAdd(&s_cnt[i0], 1);
        atomicAdd(&s_cnt[i1], 1);
    }
    __syncthreads();
    if (tid == 0) {
        int a = 0;
        for (int e = 0; e < NE; e++) { offs[e] = a; s_cur[e] = a; a += s_cnt[e]; }
        offs[NE] = a;
    }
    __syncthreads();
    for (int t = tid; t < T_TOKENS; t += 256) {
        int i0 = s_e0[t], i1 = s_e1[t];
        float w0 = s_w0[t];
        int sl0 = atomicAdd(&s_cur[i0], 1);
        pair_tok[sl0] = t; pair_w[sl0] = w0;
        int sl1 = atomicAdd(&s_cur[i1], 1);
        pair_tok[sl1] = t; pair_w[sl1] = 1.f - w0;
    }
}

// ---------------- fp32 -> bf16 convert of x ----------------
__global__ void cvt_x_kernel(const float* __restrict__ x, u16* __restrict__ xb) {
    int i = blockIdx.x * 256 + threadIdx.x;
    float4 v = ((const float4*)x)[i];
    ushort4 b;
    b.x = f2b(v.x); b.y = f2b(v.y); b.z = f2b(v.z); b.w = f2b(v.w);
    ((ushort4*)xb)[i] = b;
}

// ---------------- all-weights transpose+convert: W[e][K][N] f32 -> Wt[e][N][K] bf16 ----------------
__global__ __launch_bounds__(256) void transpose_all(const float* __restrict__ wi0,
                                                     const float* __restrict__ wi1,
                                                     const float* __restrict__ wo,
                                                     u16* __restrict__ wt0,
                                                     u16* __restrict__ wt1,
                                                     u16* __restrict__ wto) {
    int wsel = blockIdx.y >> 3, e = blockIdx.y & 7;
    const float* W; u16* Wt; int K, N, nb, kb;
    int bx = blockIdx.x;
    if (wsel == 0)      { W = wi0; Wt = wt0; }
    else if (wsel == 1) { W = wi1; Wt = wt1; }
    else                { W = wo;  Wt = wto; }
    if (wsel < 2) { K = HID; N = INTER_; nb = (bx & 31) * 64; kb = (bx >> 5) * 64; }
    else          { K = INTER_; N = HID; nb = (bx & 15) * 64; kb = (bx >> 4) * 64; }
    const float* Win = W + (size_t)e * K * N;
    u16* Wout = Wt + (size_t)e * N * K;
    __shared__ __align__(16) u16 tile[64 * 68];
    int tid = threadIdx.x;
#pragma unroll
    for (int p = 0; p < 4; p++) {
        int c = tid + p * 256;
        int r = c >> 4, c4 = c & 15;
        float4 v = *(const float4*)&Win[(size_t)(kb + r) * N + nb + c4 * 4];
        ushort4 b;
        b.x = f2b(v.x); b.y = f2b(v.y); b.z = f2b(v.z); b.w = f2b(v.w);
        *(ushort4*)&tile[r * 68 + c4 * 4] = b;
    }
    __syncthreads();
#pragma unroll
    for (int p = 0; p < 2; p++) {
        int k8 = p * 4 + (tid >> 6);   // wave-uniform
        int n = tid & 63;
        __align__(16) u16 tmp[8];
#pragma unroll
        for (int j = 0; j < 8; j++) tmp[j] = tile[(k8 * 8 + j) * 68 + n];
        *(uint4*)&Wout[(size_t)(nb + n) * K + kb + k8 * 8] = *(const uint4*)tmp;
    }
}

// ---------------- fused up-proj: intr = silu(x@wi0) * (x@wi1) ----------------
// BK=64, XOR-8 source swizzle so fragment ds_read_b128s are conflict-free.
// LDS rows: 128B stride; physical 16B chunk p of row r holds global chunk p^(r&7).
__global__ __launch_bounds__(256, 2) void fused_up_kernel(
        const u16* __restrict__ A, const u16* __restrict__ B0t, const u16* __restrict__ B1t,
        const int* __restrict__ pair_tok, const int* __restrict__ offs,
        u16* __restrict__ intr) {
    int e = blockIdx.z;
    int off = offs[e];
    int cnt = offs[e + 1] - off;
    int row0 = blockIdx.y * 128;
    if (row0 >= cnt) return;
    int nt = blockIdx.x * 128;

    __shared__ __align__(16) u16 As[128 * 64];
    __shared__ __align__(16) u16 Bs0[128 * 64];
    __shared__ __align__(16) u16 Bs1[128 * 64];

    int tid = threadIdx.x;
    int wave = tid >> 6, lane = tid & 63;

    const u16 *gA[4], *gB0[4], *gB1[4];
    u16 *lA[4], *lB0[4], *lB1[4];
    const size_t eNK = (size_t)e * INTER_ * HID;
#pragma unroll
    for (int is = 0; is < 4; is++) {
        int c = wave * 4 + is;                 // chunk 0..15 (8 rows x 128B each)
        int r = c * 8 + (lane >> 3);
        int sg = (lane & 7) ^ (r & 7);         // swizzled source 16B segment
        int mr = row0 + r; if (mr > cnt - 1) mr = cnt - 1;
        int arow = pair_tok[off + mr];
        gA[is]  = A + (size_t)arow * HID + sg * 8;
        gB0[is] = B0t + eNK + (size_t)(nt + r) * HID + sg * 8;
        gB1[is] = B1t + eNK + (size_t)(nt + r) * HID + sg * 8;
        lA[is]  = As  + c * 512;
        lB0[is] = Bs0 + c * 512;
        lB1[is] = Bs1 + c * 512;
    }

    int wr = (wave >> 1) * 64, wc = (wave & 1) * 64;
    int fm = lane & 15, quad = lane >> 4;

    f32x4 acc0[4][4], acc1[4][4];
#pragma unroll
    for (int i = 0; i < 4; i++)
#pragma unroll
        for (int j = 0; j < 4; j++) {
            acc0[i][j] = (f32x4){0.f, 0.f, 0.f, 0.f};
            acc1[i][j] = (f32x4){0.f, 0.f, 0.f, 0.f};
        }

    for (int kb = 0; kb < HID; kb += 64) {
#pragma unroll
        for (int is = 0; is < 4; is++) {
            gl_lds16(gA[is] + kb, lA[is]);
            gl_lds16(gB0[is] + kb, lB0[is]);
            gl_lds16(gB1[is] + kb, lB1[is]);
        }
        __syncthreads();
#pragma unroll
        for (int step = 0; step < 2; step++) {
            int f = step * 4 + quad;           // desired global 16B chunk
            s16x8 af[4];
#pragma unroll
            for (int i = 0; i < 4; i++) {
                int R = wr + i * 16 + fm;
                af[i] = *(const s16x8*)&As[R * 64 + ((f ^ (R & 7)) * 8)];
            }
#pragma unroll
            for (int j = 0; j < 4; j++) {
                int R = wc + j * 16 + fm;
                s16x8 b0 = *(const s16x8*)&Bs0[R * 64 + ((f ^ (R & 7)) * 8)];
                s16x8 b1 = *(const s16x8*)&Bs1[R * 64 + ((f ^ (R & 7)) * 8)];
#pragma unroll
                for (int i = 0; i < 4; i++) {
                    acc0[i][j] = __builtin_amdgcn_mfma_f32_16x16x32_bf16(af[i], b0, acc0[i][j], 0, 0, 0);
                    acc1[i][j] = __builtin_amdgcn_mfma_f32_16x16x32_bf16(af[i], b1, acc1[i][j], 0, 0, 0);
                }
            }
        }
        __syncthreads();
    }

    // epilogue: C/D layout col=lane&15, row=(lane>>4)*4+reg; fused SwiGLU
    int r4 = quad * 4, cc = lane & 15;
#pragma unroll
    for (int i = 0; i < 4; i++) {
#pragma unroll
        for (int reg = 0; reg < 4; reg++) {
            int rr = wr + i * 16 + r4 + reg;
            if (row0 + rr < cnt) {
                size_t slot = (size_t)(off + row0 + rr);
#pragma unroll
                for (int j = 0; j < 4; j++) {
                    int col = nt + wc + j * 16 + cc;
                    float a = acc0[i][j][reg];
                    float b = acc1[i][j][reg];
                    float s = a / (1.f + __expf(-a)) * b;
                    intr[slot * INTER_ + col] = f2b(s);
                }
            }
        }
    }
}

// ---------------- down-proj: out[t] += w * (intr @ wo), split-K=2, atomic epilogue ----------------
__global__ __launch_bounds__(256, 2) void down_kernel(
        const u16* __restrict__ A, const u16* __restrict__ Bt,
        const int* __restrict__ offs, const int* __restrict__ pair_tok,
        const float* __restrict__ pair_w, float* __restrict__ out) {
    int e = blockIdx.z >> 1, ks = blockIdx.z & 1;
    int off = offs[e];
    int cnt = offs[e + 1] - off;
    int row0 = blockIdx.y * 128;
    if (row0 >= cnt) return;
    int nt = blockIdx.x * 128;

    __shared__ __align__(16) u16 As[128 * 64];
    __shared__ __align__(16) u16 Bs[128 * 64];

    int tid = threadIdx.x;
    int wave = tid >> 6, lane = tid & 63;

    const u16 *gA[4], *gB[4];
    u16 *lA[4], *lB[4];
    const size_t eNK = (size_t)e * HID * INTER_;
#pragma unroll
    for (int is = 0; is < 4; is++) {
        int c = wave * 4 + is;
        int r = c * 8 + (lane >> 3);
        int sg = (lane & 7) ^ (r & 7);
        int mr = row0 + r; if (mr > cnt - 1) mr = cnt - 1;
        gA[is] = A + (size_t)(off + mr) * INTER_ + sg * 8;
        gB[is] = Bt + eNK + (size_t)(nt + r) * INTER_ + sg * 8;
        lA[is] = As + c * 512;
        lB[is] = Bs + c * 512;
    }

    int wr = (wave >> 1) * 64, wc = (wave & 1) * 64;
    int fm = lane & 15, quad = lane >> 4;

    f32x4 acc[4][4];
#pragma unroll
    for (int i = 0; i < 4; i++)
#pragma unroll
        for (int j = 0; j < 4; j++) acc[i][j] = (f32x4){0.f, 0.f, 0.f, 0.f};

    int kend = ks * 1024 + 1024;
    for (int kb = ks * 1024; kb < kend; kb += 64) {
#pragma unroll
        for (int is = 0; is < 4; is++) {
            gl_lds16(gA[is] + kb, lA[is]);
            gl_lds16(gB[is] + kb, lB[is]);
        }
        __syncthreads();
#pragma unroll
        for (int step = 0; step < 2; step++) {
            int f = step * 4 + quad;
            s16x8 af[4], bfr[4];
#pragma unroll
            for (int i = 0; i < 4; i++) {
                int R = wr + i * 16 + fm;
                af[i] = *(const s16x8*)&As[R * 64 + ((f ^ (R & 7)) * 8)];
            }
#pragma unroll
            for (int j = 0; j < 4; j++) {
                int R = wc + j * 16 + fm;
                bfr[j] = *(const s16x8*)&Bs[R * 64 + ((f ^ (R & 7)) * 8)];
            }
#pragma unroll
            for (int i = 0; i < 4; i++)
#pragma unroll
                for (int j = 0; j < 4; j++)
                    acc[i][j] = __builtin_amdgcn_mfma_f32_16x16x32_bf16(af[i], bfr[j], acc[i][j], 0, 0, 0);
        }
        __syncthreads();
    }

    int r4 = quad * 4, cc = lane & 15;
#pragma unroll
    for (int i = 0; i < 4; i++) {
#pragma unroll
        for (int reg = 0; reg < 4; reg++) {
            int rr = wr + i * 16 + r4 + reg;
            if (row0 + rr < cnt) {
                int slot = off + row0 + rr;
                int t = pair_tok[slot];
                float w = pair_w[slot];
#pragma unroll
                for (int j = 0; j < 4; j++) {
                    int col = nt + wc + j * 16 + cc;
                    atomicAdd(&out[(size_t)t * HID + col], w * acc[i][j][reg]);
                }
            }
        }
    }
}

extern "C" void kernel_launch(void* const* d_in, const int* in_sizes, int n_in,
                              void* d_out, int out_size, void* d_ws, size_t ws_size,
                              hipStream_t stream) {
    (void)in_sizes; (void)n_in; (void)ws_size;
    const float* x   = (const float*)d_in[0];
    const float* rl  = (const float*)d_in[1];
    const float* wi0 = (const float*)d_in[2];
    const float* wi1 = (const float*)d_in[3];
    const float* wo  = (const float*)d_in[4];
    float* out = (float*)d_out;

    char* p = (char*)d_ws;
    auto alloc = [&](size_t bytes) -> void* {
        void* r = (void*)p;
        p += (bytes + 255) & ~(size_t)255;
        return r;
    };
    u16* xb   = (u16*)alloc((size_t)T_TOKENS * HID * 2);          // 4 MB
    u16* wt0  = (u16*)alloc((size_t)NE * HID * INTER_ * 2);       // 32 MB  [E][I][H]
    u16* wt1  = (u16*)alloc((size_t)NE * HID * INTER_ * 2);       // 32 MB
    u16* wto  = (u16*)alloc((size_t)NE * HID * INTER_ * 2);       // 32 MB  [E][H][I]
    u16* intr = (u16*)alloc((size_t)NPAIR * INTER_ * 2);          // 16 MB
    int* offs     = (int*)alloc((NE + 1) * sizeof(int));
    int* pair_tok = (int*)alloc(NPAIR * sizeof(int));
    float* pair_w = (float*)alloc(NPAIR * sizeof(float));

    hipMemsetAsync(out, 0, (size_t)out_size * sizeof(float), stream);
    route_all<<<1, 256, 0, stream>>>(rl, offs, pair_tok, pair_w);
    cvt_x_kernel<<<T_TOKENS * HID / 4 / 256, 256, 0, stream>>>(x, xb);
    transpose_all<<<dim3(512, 24), 256, 0, stream>>>(wi0, wi1, wo, wt0, wt1, wto);

    dim3 g1(INTER_ / 128, 16, NE);
    fused_up_kernel<<<g1, 256, 0, stream>>>(xb, wt0, wt1, pair_tok, offs, intr);
    dim3 g2(HID / 128, 16, NE * 2);
    down_kernel<<<g2, 256, 0, stream>>>(intr, wto, offs, pair_tok, pair_w, out);
}

// Round 4
// 330.964 us; speedup vs baseline: 1.3350x; 1.0552x over previous
//
#include <hip/hip_runtime.h>
#include <hip/hip_bf16.h>

#define T_TOKENS 2048
#define NE 8
#define HID 1024
#define INTER_ 2048
#define NPAIR (T_TOKENS * 2)

typedef unsigned short u16;
typedef __attribute__((ext_vector_type(4))) float f32x4;
typedef __attribute__((ext_vector_type(8))) short s16x8;

__device__ __forceinline__ u16 f2b(float f) {
    union { float f; unsigned u; } v; v.f = f;
    unsigned r = v.u + 0x7fffu + ((v.u >> 16) & 1u);
    return (u16)(r >> 16);
}

// async global->LDS, 16B per lane; LDS dest is wave-uniform base + lane*16
__device__ __forceinline__ void gl_lds16(const u16* g, u16* l) {
    __builtin_amdgcn_global_load_lds(
        (const __attribute__((address_space(1))) unsigned int*)g,
        (__attribute__((address_space(3))) unsigned int*)l, 16, 0, 0);
}

// ---------------- routing: top2 + softmax + grouped scatter, one block ----------------
__global__ __launch_bounds__(256) void route_all(const float* __restrict__ logits,
                                                 int* __restrict__ offs,
                                                 int* __restrict__ pair_tok,
                                                 float* __restrict__ pair_w,
                                                 int* __restrict__ pair_slot,
                                                 float* __restrict__ tokW) {
    __shared__ int s_cnt[NE];
    __shared__ int s_cur[NE];
    __shared__ short s_e0[T_TOKENS];
    __shared__ short s_e1[T_TOKENS];
    __shared__ float s_w0[T_TOKENS];
    int tid = threadIdx.x;
    if (tid < NE) s_cnt[tid] = 0;
    __syncthreads();
    for (int t = tid; t < T_TOKENS; t += 256) {
        float l[NE];
#pragma unroll
        for (int i = 0; i < NE; i++) l[i] = logits[t * NE + i];
        int i0 = 0; float m0 = l[0];
#pragma unroll
        for (int i = 1; i < NE; i++) if (l[i] > m0) { m0 = l[i]; i0 = i; }
        int i1 = -1; float m1 = -1e30f;
#pragma unroll
        for (int i = 0; i < NE; i++) if (i != i0 && l[i] > m1) { m1 = l[i]; i1 = i; }
        float w0 = 1.f / (1.f + __expf(m1 - m0));
        s_e0[t] = (short)i0; s_e1[t] = (short)i1; s_w0[t] = w0;
        atomicAdd(&s_cnt[i0], 1);
        atomicAdd(&s_cnt[i1], 1);
    }
    __syncthreads();
    if (tid == 0) {
        int a = 0;
        for (int e = 0; e < NE; e++) { offs[e] = a; s_cur[e] = a; a += s_cnt[e]; }
        offs[NE] = a;
    }
    __syncthreads();
    for (int t = tid; t < T_TOKENS; t += 256) {
        int i0 = s_e0[t], i1 = s_e1[t];
        float w0 = s_w0[t];
        int sl0 = atomicAdd(&s_cur[i0], 1);
        pair_tok[sl0] = t; pair_w[sl0] = w0;
        pair_slot[2 * t] = sl0; tokW[2 * t] = w0;
        int sl1 = atomicAdd(&s_cur[i1], 1);
        pair_tok[sl1] = t; pair_w[sl1] = 1.f - w0;
        pair_slot[2 * t + 1] = sl1; tokW[2 * t + 1] = 1.f - w0;
    }
}

// ---------------- fp32 -> bf16 convert of x ----------------
__global__ void cvt_x_kernel(const float* __restrict__ x, u16* __restrict__ xb) {
    int i = blockIdx.x * 256 + threadIdx.x;
    float4 v = ((const float4*)x)[i];
    ushort4 b;
    b.x = f2b(v.x); b.y = f2b(v.y); b.z = f2b(v.z); b.w = f2b(v.w);
    ((ushort4*)xb)[i] = b;
}

// ---------------- all-weights transpose+convert: W[e][K][N] f32 -> Wt[e][N][K] bf16 ----------------
// Phase1: coalesced float4 reads (4 full rows x 256B per wave-instr), in-register 4x4
// micro-transpose, ds_write_b64 into [n][k] LDS image. Phase2: ds_read_b128 + stores
// where 4 consecutive lanes fully cover each 64B output line (no partial sectors).
#define TSTR 72   // u16 stride of LDS image row (144 B, keeps 16B alignment)
__global__ __launch_bounds__(256) void transpose_all(const float* __restrict__ wi0,
                                                     const float* __restrict__ wi1,
                                                     const float* __restrict__ wo,
                                                     u16* __restrict__ wt0,
                                                     u16* __restrict__ wt1,
                                                     u16* __restrict__ wto) {
    int wsel = blockIdx.y >> 3, e = blockIdx.y & 7;
    const float* W; u16* Wt; int K, N, nb, kb;
    int bx = blockIdx.x;
    if (wsel == 0)      { W = wi0; Wt = wt0; }
    else if (wsel == 1) { W = wi1; Wt = wt1; }
    else                { W = wo;  Wt = wto; }
    if (wsel < 2) { K = HID; N = INTER_; nb = (bx & 31) * 64; kb = (bx >> 5) * 64; }
    else          { K = INTER_; N = HID; nb = (bx & 15) * 64; kb = (bx >> 4) * 64; }
    const float* Win = W + (size_t)e * K * N;
    u16* Wout = Wt + (size_t)e * N * K;
    __shared__ __align__(16) u16 tile[64 * TSTR];
    int tid = threadIdx.x;
    {
        int n4 = (tid & 15) * 4;
        int k4 = (tid >> 4) * 4;
        float4 v[4];
#pragma unroll
        for (int j = 0; j < 4; j++)
            v[j] = *(const float4*)&Win[(size_t)(kb + k4 + j) * N + nb + n4];
#pragma unroll
        for (int i = 0; i < 4; i++) {
            ushort4 o;
            o.x = f2b(((const float*)&v[0])[i]);
            o.y = f2b(((const float*)&v[1])[i]);
            o.z = f2b(((const float*)&v[2])[i]);
            o.w = f2b(((const float*)&v[3])[i]);
            *(ushort4*)&tile[(n4 + i) * TSTR + k4] = o;
        }
    }
    __syncthreads();
    {
        int n = tid >> 2, ks = tid & 3;
#pragma unroll
        for (int c = 0; c < 2; c++) {
            uint4 v = *(const uint4*)&tile[n * TSTR + ks * 8 + 32 * c];
            *(uint4*)&Wout[(size_t)(nb + n) * K + kb + ks * 8 + 32 * c] = v;
        }
    }
}

// ---------------- fused up-proj: intr = silu(x@wi0) * (x@wi1) ----------------
// BK=64, XOR-8 source swizzle so fragment ds_read_b128s are conflict-free.
__global__ __launch_bounds__(256, 2) void fused_up_kernel(
        const u16* __restrict__ A, const u16* __restrict__ B0t, const u16* __restrict__ B1t,
        const int* __restrict__ pair_tok, const int* __restrict__ offs,
        u16* __restrict__ intr) {
    int e = blockIdx.z;
    int off = offs[e];
    int cnt = offs[e + 1] - off;
    int row0 = blockIdx.y * 128;
    if (row0 >= cnt) return;
    int nt = blockIdx.x * 128;

    __shared__ __align__(16) u16 As[128 * 64];
    __shared__ __align__(16) u16 Bs0[128 * 64];
    __shared__ __align__(16) u16 Bs1[128 * 64];

    int tid = threadIdx.x;
    int wave = tid >> 6, lane = tid & 63;

    const u16 *gA[4], *gB0[4], *gB1[4];
    u16 *lA[4], *lB0[4], *lB1[4];
    const size_t eNK = (size_t)e * INTER_ * HID;
#pragma unroll
    for (int is = 0; is < 4; is++) {
        int c = wave * 4 + is;
        int r = c * 8 + (lane >> 3);
        int sg = (lane & 7) ^ (r & 7);
        int mr = row0 + r; if (mr > cnt - 1) mr = cnt - 1;
        int arow = pair_tok[off + mr];
        gA[is]  = A + (size_t)arow * HID + sg * 8;
        gB0[is] = B0t + eNK + (size_t)(nt + r) * HID + sg * 8;
        gB1[is] = B1t + eNK + (size_t)(nt + r) * HID + sg * 8;
        lA[is]  = As  + c * 512;
        lB0[is] = Bs0 + c * 512;
        lB1[is] = Bs1 + c * 512;
    }

    int wr = (wave >> 1) * 64, wc = (wave & 1) * 64;
    int fm = lane & 15, quad = lane >> 4;

    f32x4 acc0[4][4], acc1[4][4];
#pragma unroll
    for (int i = 0; i < 4; i++)
#pragma unroll
        for (int j = 0; j < 4; j++) {
            acc0[i][j] = (f32x4){0.f, 0.f, 0.f, 0.f};
            acc1[i][j] = (f32x4){0.f, 0.f, 0.f, 0.f};
        }

    for (int kb = 0; kb < HID; kb += 64) {
#pragma unroll
        for (int is = 0; is < 4; is++) {
            gl_lds16(gA[is] + kb, lA[is]);
            gl_lds16(gB0[is] + kb, lB0[is]);
            gl_lds16(gB1[is] + kb, lB1[is]);
        }
        __syncthreads();
#pragma unroll
        for (int step = 0; step < 2; step++) {
            int f = step * 4 + quad;
            s16x8 af[4];
#pragma unroll
            for (int i = 0; i < 4; i++) {
                int R = wr + i * 16 + fm;
                af[i] = *(const s16x8*)&As[R * 64 + ((f ^ (R & 7)) * 8)];
            }
#pragma unroll
            for (int j = 0; j < 4; j++) {
                int R = wc + j * 16 + fm;
                s16x8 b0 = *(const s16x8*)&Bs0[R * 64 + ((f ^ (R & 7)) * 8)];
                s16x8 b1 = *(const s16x8*)&Bs1[R * 64 + ((f ^ (R & 7)) * 8)];
#pragma unroll
                for (int i = 0; i < 4; i++) {
                    acc0[i][j] = __builtin_amdgcn_mfma_f32_16x16x32_bf16(af[i], b0, acc0[i][j], 0, 0, 0);
                    acc1[i][j] = __builtin_amdgcn_mfma_f32_16x16x32_bf16(af[i], b1, acc1[i][j], 0, 0, 0);
                }
            }
        }
        __syncthreads();
    }

    int r4 = quad * 4, cc = lane & 15;
#pragma unroll
    for (int i = 0; i < 4; i++) {
#pragma unroll
        for (int reg = 0; reg < 4; reg++) {
            int rr = wr + i * 16 + r4 + reg;
            if (row0 + rr < cnt) {
                size_t slot = (size_t)(off + row0 + rr);
#pragma unroll
                for (int j = 0; j < 4; j++) {
                    int col = nt + wc + j * 16 + cc;
                    float a = acc0[i][j][reg];
                    float b = acc1[i][j][reg];
                    float s = a / (1.f + __expf(-a)) * b;
                    intr[slot * INTER_ + col] = f2b(s);
                }
            }
        }
    }
}

// ---------------- down-proj: ypart[ks] = intr @ wo (split-K=2, plain stores) ----------------
__global__ __launch_bounds__(256, 2) void down_kernel(
        const u16* __restrict__ A, const u16* __restrict__ Bt,
        const int* __restrict__ offs, float* __restrict__ ypart) {
    int e = blockIdx.z >> 1, ks = blockIdx.z & 1;
    int off = offs[e];
    int cnt = offs[e + 1] - off;
    int row0 = blockIdx.y * 128;
    if (row0 >= cnt) return;
    int nt = blockIdx.x * 128;

    __shared__ __align__(16) u16 As[128 * 64];
    __shared__ __align__(16) u16 Bs[128 * 64];

    int tid = threadIdx.x;
    int wave = tid >> 6, lane = tid & 63;

    const u16 *gA[4], *gB[4];
    u16 *lA[4], *lB[4];
    const size_t eNK = (size_t)e * HID * INTER_;
#pragma unroll
    for (int is = 0; is < 4; is++) {
        int c = wave * 4 + is;
        int r = c * 8 + (lane >> 3);
        int sg = (lane & 7) ^ (r & 7);
        int mr = row0 + r; if (mr > cnt - 1) mr = cnt - 1;
        gA[is] = A + (size_t)(off + mr) * INTER_ + sg * 8;
        gB[is] = Bt + eNK + (size_t)(nt + r) * INTER_ + sg * 8;
        lA[is] = As + c * 512;
        lB[is] = Bs + c * 512;
    }

    int wr = (wave >> 1) * 64, wc = (wave & 1) * 64;
    int fm = lane & 15, quad = lane >> 4;

    f32x4 acc[4][4];
#pragma unroll
    for (int i = 0; i < 4; i++)
#pragma unroll
        for (int j = 0; j < 4; j++) acc[i][j] = (f32x4){0.f, 0.f, 0.f, 0.f};

    int kend = ks * 1024 + 1024;
    for (int kb = ks * 1024; kb < kend; kb += 64) {
#pragma unroll
        for (int is = 0; is < 4; is++) {
            gl_lds16(gA[is] + kb, lA[is]);
            gl_lds16(gB[is] + kb, lB[is]);
        }
        __syncthreads();
#pragma unroll
        for (int step = 0; step < 2; step++) {
            int f = step * 4 + quad;
            s16x8 af[4], bfr[4];
#pragma unroll
            for (int i = 0; i < 4; i++) {
                int R = wr + i * 16 + fm;
                af[i] = *(const s16x8*)&As[R * 64 + ((f ^ (R & 7)) * 8)];
            }
#pragma unroll
            for (int j = 0; j < 4; j++) {
                int R = wc + j * 16 + fm;
                bfr[j] = *(const s16x8*)&Bs[R * 64 + ((f ^ (R & 7)) * 8)];
            }
#pragma unroll
            for (int i = 0; i < 4; i++)
#pragma unroll
                for (int j = 0; j < 4; j++)
                    acc[i][j] = __builtin_amdgcn_mfma_f32_16x16x32_bf16(af[i], bfr[j], acc[i][j], 0, 0, 0);
        }
        __syncthreads();
    }

    int r4 = quad * 4, cc = lane & 15;
    float* yout = ypart + (size_t)ks * NPAIR * HID;
#pragma unroll
    for (int i = 0; i < 4; i++) {
#pragma unroll
        for (int reg = 0; reg < 4; reg++) {
            int rr = wr + i * 16 + r4 + reg;
            if (row0 + rr < cnt) {
                size_t slot = (size_t)(off + row0 + rr);
#pragma unroll
                for (int j = 0; j < 4; j++) {
                    int col = nt + wc + j * 16 + cc;
                    yout[slot * HID + col] = acc[i][j][reg];
                }
            }
        }
    }
}

// ---------------- weighted combine (sums the two split-K partials) ----------------
__global__ void combine_kernel(const float* __restrict__ y0, const float* __restrict__ y1,
                               const int* __restrict__ pair_slot,
                               const float* __restrict__ tokW, float* __restrict__ out) {
    int i = blockIdx.x * 256 + threadIdx.x;
    int t = i >> 8;
    int h4 = i & 255;
    int s0 = pair_slot[2 * t], s1 = pair_slot[2 * t + 1];
    float w0 = tokW[2 * t], w1 = tokW[2 * t + 1];
    float4 a0 = ((const float4*)y0)[(size_t)s0 * 256 + h4];
    float4 a1 = ((const float4*)y1)[(size_t)s0 * 256 + h4];
    float4 b0 = ((const float4*)y0)[(size_t)s1 * 256 + h4];
    float4 b1 = ((const float4*)y1)[(size_t)s1 * 256 + h4];
    float4 r;
    r.x = w0 * (a0.x + a1.x) + w1 * (b0.x + b1.x);
    r.y = w0 * (a0.y + a1.y) + w1 * (b0.y + b1.y);
    r.z = w0 * (a0.z + a1.z) + w1 * (b0.z + b1.z);
    r.w = w0 * (a0.w + a1.w) + w1 * (b0.w + b1.w);
    ((float4*)out)[i] = r;
}

extern "C" void kernel_launch(void* const* d_in, const int* in_sizes, int n_in,
                              void* d_out, int out_size, void* d_ws, size_t ws_size,
                              hipStream_t stream) {
    (void)in_sizes; (void)n_in; (void)out_size; (void)ws_size;
    const float* x   = (const float*)d_in[0];
    const float* rl  = (const float*)d_in[1];
    const float* wi0 = (const float*)d_in[2];
    const float* wi1 = (const float*)d_in[3];
    const float* wo  = (const float*)d_in[4];
    float* out = (float*)d_out;

    char* p = (char*)d_ws;
    auto alloc = [&](size_t bytes) -> void* {
        void* r = (void*)p;
        p += (bytes + 255) & ~(size_t)255;
        return r;
    };
    u16* xb   = (u16*)alloc((size_t)T_TOKENS * HID * 2);          // 4 MB
    u16* wt0  = (u16*)alloc((size_t)NE * HID * INTER_ * 2);       // 32 MB  [E][I][H]
    u16* wt1  = (u16*)alloc((size_t)NE * HID * INTER_ * 2);       // 32 MB
    u16* wto  = (u16*)alloc((size_t)NE * HID * INTER_ * 2);       // 32 MB  [E][H][I]
    u16* intr = (u16*)alloc((size_t)NPAIR * INTER_ * 2);          // 16 MB
    float* ypart = (float*)alloc((size_t)2 * NPAIR * HID * 4);    // 32 MB
    int* offs     = (int*)alloc((NE + 1) * sizeof(int));
    int* pair_tok = (int*)alloc(NPAIR * sizeof(int));
    float* pair_w = (float*)alloc(NPAIR * sizeof(float));
    int* pair_slot= (int*)alloc(NPAIR * sizeof(int));
    float* tokW   = (float*)alloc(NPAIR * sizeof(float));

    route_all<<<1, 256, 0, stream>>>(rl, offs, pair_tok, pair_w, pair_slot, tokW);
    cvt_x_kernel<<<T_TOKENS * HID / 4 / 256, 256, 0, stream>>>(x, xb);
    transpose_all<<<dim3(512, 24), 256, 0, stream>>>(wi0, wi1, wo, wt0, wt1, wto);

    dim3 g1(INTER_ / 128, 16, NE);
    fused_up_kernel<<<g1, 256, 0, stream>>>(xb, wt0, wt1, pair_tok, offs, intr);
    dim3 g2(HID / 128, 16, NE * 2);
    down_kernel<<<g2, 256, 0, stream>>>(intr, wto, offs, ypart);
    combine_kernel<<<T_TOKENS * HID / 4 / 256, 256, 0, stream>>>(
        ypart, ypart + (size_t)NPAIR * HID, pair_slot, tokW, out);
}